// Round 18
// baseline (41.577 us; speedup 1.0000x reference)
//
#include <hip/hip_runtime.h>
#include <math.h>

// Problem constants (reference: POS_LEN=32, NUM_F=16, HIDDEN=256, T=32)
#define NUM_F   16
#define FIN     (8 * NUM_F)      // 128 fourier features
#define HIDDEN  256
#define TOUT    32
#define NOFF    63               // distinct offset values: -31..31
#define NSUM    125              // distinct dr+dc / dr-dc values: -62..62
#define NPAIRS_TBL (NOFF * NOFF) // 3969
#define PROWS   (NOFF + NOFF + NSUM + NSUM)      // 376 rows in P

// ---------------------------------------------------------------------------
// KP: layer-1 separable partials P[rho][h] (proven ~1.5 us, plain stores).
__global__ __launch_bounds__(256) void gab_ptab_kernel(
    const float* __restrict__ freqs, const float* __restrict__ W1,
    float* __restrict__ P)
{
    __shared__ float fv[32];
    const int rho = blockIdx.x;
    int grp, val;
    if (rho < NOFF)                 { grp = 0; val = rho - 31; }
    else if (rho < 2 * NOFF)        { grp = 1; val = rho - NOFF - 31; }
    else if (rho < 2 * NOFF + NSUM) { grp = 2; val = rho - 2 * NOFF - 62; }
    else                            { grp = 3; val = rho - 2 * NOFF - NSUM - 62; }
    const int t = threadIdx.x;
    if (t < 32) {
        const float arg = (float)val * freqs[t & 15];
        fv[t] = (t < 16) ? sinf(arg) : cosf(arg);   // [sin16, cos16]
    }
    __syncthreads();
    const float4* __restrict__ w4 = (const float4*)(W1 + t * FIN + grp * 32);
    const float4* f4 = (const float4*)fv;           // same-addr broadcast
    float a0 = 0.f, a1 = 0.f, a2 = 0.f, a3 = 0.f;
    #pragma unroll
    for (int k = 0; k < 8; k += 2) {
        const float4 wa = w4[k], wb = w4[k + 1];
        const float4 fa = f4[k], fb = f4[k + 1];
        a0 = fmaf(wa.x, fa.x, a0); a1 = fmaf(wa.y, fa.y, a1);
        a2 = fmaf(wa.z, fa.z, a2); a3 = fmaf(wa.w, fa.w, a3);
        a0 = fmaf(wb.x, fb.x, a0); a1 = fmaf(wb.y, fb.y, a1);
        a2 = fmaf(wb.z, fb.z, a2); a3 = fmaf(wb.w, fb.w, a3);
    }
    P[rho * HIDDEN + t] = (a0 + a1) + (a2 + a3);
}

// ---------------------------------------------------------------------------
// KT v5: 249 blocks x 16 pairs (wave w owns 4 sequential pairs).
//  - W2 staged to LDS ONCE per 16 pairs (traffic / 4 vs R14).
//  - register double-buffered P prefetch: pair q+1's 4 f4 loads issue before
//    pair q's compute -> cold-miss latency hides under compute.
//  - layer-2: R14's proven LDS b128 reads + halving shuffle reduce.
__global__ __launch_bounds__(256, 2) void gab_table_kernel(
    const float* __restrict__ P, const float* __restrict__ b1,
    const float* __restrict__ W2, const float* __restrict__ b2,
    float* __restrict__ table)
{
    __shared__ float4 w2s[2048];                  // 32 KB: all of W2 as f4

    const int t = threadIdx.x;
    const int w = t >> 6;
    const int l = t & 63;
    const int pbase = blockIdx.x * 16 + w * 4;    // this wave's 4 pairs

    const float4* __restrict__ P4  = (const float4*)P;
    const float4* __restrict__ W24 = (const float4*)W2;
    const float4 bb = ((const float4*)b1)[l];

    // ---- prefetch pair 0 (issues before staging stalls) ------------------
    int cp = (pbase < NPAIRS_TBL) ? pbase : (NPAIRS_TBL - 1);
    int ia = cp / NOFF, ib = cp % NOFF;
    float4 pa = P4[ia * 64 + l];
    float4 pb = P4[(NOFF + ib) * 64 + l];
    float4 pp = P4[(2 * NOFF + ia + ib) * 64 + l];
    float4 pm = P4[(2 * NOFF + NSUM + ia - ib + 62) * 64 + l];

    // ---- stage W2 -> LDS (coalesced, 8 f4/thread) -------------------------
    #pragma unroll
    for (int k = 0; k < 8; ++k) w2s[k * 256 + t] = W24[k * 256 + t];
    __syncthreads();

    #pragma unroll
    for (int q = 0; q < 4; ++q) {
        const int pair = pbase + q;

        // prefetch next pair's P rows (hides under this pair's compute)
        float4 na, nb, np, nm;
        if (q < 3) {
            const int cpn = (pair + 1 < NPAIRS_TBL) ? pair + 1 : (NPAIRS_TBL - 1);
            const int ja = cpn / NOFF, jb = cpn % NOFF;
            na = P4[ja * 64 + l];
            nb = P4[(NOFF + jb) * 64 + l];
            np = P4[(2 * NOFF + ja + jb) * 64 + l];
            nm = P4[(2 * NOFF + NSUM + ja - jb + 62) * 64 + l];
        }

        // hidden: h[4l..4l+3]
        float h0 = pa.x + pb.x + pp.x + pm.x + bb.x;
        float h1 = pa.y + pb.y + pp.y + pm.y + bb.y;
        float h2 = pa.z + pb.z + pp.z + pm.z + bb.z;
        float h3 = pa.w + pb.w + pp.w + pm.w + bb.w;
        h0 = h0 / (1.0f + expf(-h0));
        h1 = h1 / (1.0f + expf(-h1));
        h2 = h2 / (1.0f + expf(-h2));
        h3 = h3 / (1.0f + expf(-h3));

        // layer 2 from LDS (b128, conflict-free)
        float acc[32];
        #pragma unroll
        for (int o = 0; o < 32; ++o) {
            const float4 ww = w2s[o * 64 + l];
            acc[o] = fmaf(ww.x, h0, fmaf(ww.y, h1, fmaf(ww.z, h2, ww.w * h3)));
        }

        // vector-halving shuffle reduce (static indices)
        #pragma unroll
        for (int i = 0; i < 16; ++i) {
            const float keep = (l & 1) ? acc[i + 16] : acc[i];
            const float send = (l & 1) ? acc[i] : acc[i + 16];
            acc[i] = keep + __shfl_xor(send, 1);
        }
        #pragma unroll
        for (int i = 0; i < 8; ++i) {
            const float keep = (l & 2) ? acc[i + 8] : acc[i];
            const float send = (l & 2) ? acc[i] : acc[i + 8];
            acc[i] = keep + __shfl_xor(send, 2);
        }
        #pragma unroll
        for (int i = 0; i < 4; ++i) {
            const float keep = (l & 4) ? acc[i + 4] : acc[i];
            const float send = (l & 4) ? acc[i] : acc[i + 4];
            acc[i] = keep + __shfl_xor(send, 4);
        }
        #pragma unroll
        for (int i = 0; i < 2; ++i) {
            const float keep = (l & 8) ? acc[i + 2] : acc[i];
            const float send = (l & 8) ? acc[i] : acc[i + 2];
            acc[i] = keep + __shfl_xor(send, 8);
        }
        {
            const float keep = (l & 16) ? acc[1] : acc[0];
            const float send = (l & 16) ? acc[0] : acc[1];
            acc[0] = keep + __shfl_xor(send, 16);
        }
        const float tot = acc[0] + __shfl_xor(acc[0], 32);

        if (pair < NPAIRS_TBL && l < 32) {
            const int o = ((l & 1) << 4) | ((l & 2) << 2) | (l & 4)
                        | ((l & 8) >> 2) | ((l & 16) >> 4);   // bitrev5(l)
            table[pair * TOUT + o] = (tot + b2[o]) * 0.17677669529663687f;
        }

        pa = na; pb = nb; pp = np; pm = nm;
    }
}

// ---------------------------------------------------------------------------
// Gather (plain stores — measured ~20.8 us write floor).
__global__ __launch_bounds__(256) void gab_gather_kernel(
    const float* __restrict__ table,
    float4* __restrict__ out, int npairs)
{
    const int total = npairs * 8;
    const int stride = gridDim.x * blockDim.x;
    const float4* __restrict__ tbl4 = (const float4*)table;
    for (int idx = blockIdx.x * blockDim.x + threadIdx.x; idx < total; idx += stride) {
        const int p = idx >> 3;
        const int l = idx & 7;
        const int i = p >> 10;
        const int j = p & 1023;
        const int ir = (i >> 5) - (j >> 5) + (NOFF / 2);
        const int ic = (i & 31) - (j & 31) + (NOFF / 2);
        out[idx] = tbl4[(ir * NOFF + ic) * (TOUT / 4) + l];
    }
}

// ---------------------------------------------------------------------------
extern "C" void kernel_launch(void* const* d_in, const int* in_sizes, int n_in,
                              void* d_out, int out_size, void* d_ws, size_t ws_size,
                              hipStream_t stream) {
    // inputs: 0 seq_len 1 freqs(16) 2 W1(256*128) 3 b1(256) 4 W2(32*256)
    //         5 b2(32) 6 dr(S*S) 7 dc(S*S)
    const float* freqs = (const float*)d_in[1];
    const float* W1    = (const float*)d_in[2];
    const float* b1    = (const float*)d_in[3];
    const float* W2    = (const float*)d_in[4];
    const float* b2    = (const float*)d_in[5];
    float4* out = (float4*)d_out;

    const int npairs = in_sizes[6];                // S*S = 1024*1024

    // ws layout: [table 508 KB][P 385 KB]
    const size_t TBL_B = (size_t)NPAIRS_TBL * TOUT * 4;
    float* table = (float*)d_ws;
    float* P     = (float*)((char*)d_ws + TBL_B);

    gab_ptab_kernel  <<<PROWS, 256, 0, stream>>>(freqs, W1, P);
    gab_table_kernel <<<(NPAIRS_TBL + 15) / 16, 256, 0, stream>>>(P, b1, W2, b2, table);
    gab_gather_kernel<<<2048, 256, 0, stream>>>(table, out, npairs);
}

// Round 19
// 34.684 us; speedup vs baseline: 1.1987x; 1.1987x over previous
//
#include <hip/hip_runtime.h>
#include <math.h>

// Problem constants (reference: POS_LEN=32, NUM_F=16, HIDDEN=256, T=32)
#define NUM_F   16
#define FIN     (8 * NUM_F)      // 128 fourier features
#define HIDDEN  256
#define TOUT    32
#define NOFF    63               // distinct offset values: -31..31
#define NSUM    125              // distinct dr+dc / dr-dc values: -62..62
#define NPAIRS_TBL (NOFF * NOFF) // 3969
#define PROWS   (NOFF + NOFF + NSUM + NSUM)      // 376 rows in P

// ---------------------------------------------------------------------------
// KP: layer-1 separable partials P[rho][h] (proven ~1.5 us, plain stores).
__global__ __launch_bounds__(256) void gab_ptab_kernel(
    const float* __restrict__ freqs, const float* __restrict__ W1,
    float* __restrict__ P)
{
    __shared__ float fv[32];
    const int rho = blockIdx.x;
    int grp, val;
    if (rho < NOFF)                 { grp = 0; val = rho - 31; }
    else if (rho < 2 * NOFF)        { grp = 1; val = rho - NOFF - 31; }
    else if (rho < 2 * NOFF + NSUM) { grp = 2; val = rho - 2 * NOFF - 62; }
    else                            { grp = 3; val = rho - 2 * NOFF - NSUM - 62; }
    const int t = threadIdx.x;
    if (t < 32) {
        const float arg = (float)val * freqs[t & 15];
        fv[t] = (t < 16) ? sinf(arg) : cosf(arg);   // [sin16, cos16]
    }
    __syncthreads();
    const float4* __restrict__ w4 = (const float4*)(W1 + t * FIN + grp * 32);
    const float4* f4 = (const float4*)fv;           // same-addr broadcast
    float a0 = 0.f, a1 = 0.f, a2 = 0.f, a3 = 0.f;
    #pragma unroll
    for (int k = 0; k < 8; k += 2) {
        const float4 wa = w4[k], wb = w4[k + 1];
        const float4 fa = f4[k], fb = f4[k + 1];
        a0 = fmaf(wa.x, fa.x, a0); a1 = fmaf(wa.y, fa.y, a1);
        a2 = fmaf(wa.z, fa.z, a2); a3 = fmaf(wa.w, fa.w, a3);
        a0 = fmaf(wb.x, fb.x, a0); a1 = fmaf(wb.y, fb.y, a1);
        a2 = fmaf(wb.z, fb.z, a2); a3 = fmaf(wb.w, fb.w, a3);
    }
    P[rho * HIDDEN + t] = (a0 + a1) + (a2 + a3);
}

// ---------------------------------------------------------------------------
// Scatter v2: one BLOCK per pair. Wave 0 computes the pair's 32-float row
// (R7's proven structure), writes it to LDS; all 4 waves then stream the
// pair's (i,j) rectangle with float4 stores — 8 consecutive 128-B lines per
// wave-instruction, the same pattern as the write-floor gather. Fixes R12's
// defect (scalar stores, 1-wave issue). Compute + cold P/W2 misses hide
// under co-resident blocks' store streams.
__global__ __launch_bounds__(256) void gab_scatter_kernel(
    const float* __restrict__ P, const float* __restrict__ b1,
    const float* __restrict__ W2, const float* __restrict__ b2,
    float4* __restrict__ out)
{
    __shared__ float rowLDS[32];

    const int t    = threadIdx.x;
    const int l    = t & 63;
    const int pair = blockIdx.x;

    const int ia = pair / NOFF;               // dr + 31
    const int ib = pair % NOFF;               // dc + 31
    const int dr = ia - 31, dc = ib - 31;

    if (t < 64) {                             // wave 0: row compute
        const int ip = ia + ib;
        const int im = ia - ib + 62;
        const float4* __restrict__ P4 = (const float4*)P;
        const float4 pa = P4[(0 * NOFF          + ia) * 64 + l];
        const float4 pb = P4[(1 * NOFF          + ib) * 64 + l];
        const float4 pp = P4[(2 * NOFF          + ip) * 64 + l];
        const float4 pm = P4[((2 * NOFF + NSUM) + im) * 64 + l];
        const float4 bb = ((const float4*)b1)[l];
        float h0 = pa.x + pb.x + pp.x + pm.x + bb.x;
        float h1 = pa.y + pb.y + pp.y + pm.y + bb.y;
        float h2 = pa.z + pb.z + pp.z + pm.z + bb.z;
        float h3 = pa.w + pb.w + pp.w + pm.w + bb.w;
        h0 = h0 / (1.0f + expf(-h0));
        h1 = h1 / (1.0f + expf(-h1));
        h2 = h2 / (1.0f + expf(-h2));
        h3 = h3 / (1.0f + expf(-h3));

        float acc[32];
        const float4* __restrict__ W24 = (const float4*)W2;
        #pragma unroll
        for (int o = 0; o < 32; ++o) {
            const float4 w = W24[o * 64 + l];           // coalesced, L2-hot
            acc[o] = fmaf(w.x, h0, fmaf(w.y, h1, fmaf(w.z, h2, w.w * h3)));
        }
        #pragma unroll
        for (int i = 0; i < 16; ++i) {
            const float keep = (l & 1) ? acc[i + 16] : acc[i];
            const float send = (l & 1) ? acc[i] : acc[i + 16];
            acc[i] = keep + __shfl_xor(send, 1);
        }
        #pragma unroll
        for (int i = 0; i < 8; ++i) {
            const float keep = (l & 2) ? acc[i + 8] : acc[i];
            const float send = (l & 2) ? acc[i] : acc[i + 8];
            acc[i] = keep + __shfl_xor(send, 2);
        }
        #pragma unroll
        for (int i = 0; i < 4; ++i) {
            const float keep = (l & 4) ? acc[i + 4] : acc[i];
            const float send = (l & 4) ? acc[i] : acc[i + 4];
            acc[i] = keep + __shfl_xor(send, 4);
        }
        #pragma unroll
        for (int i = 0; i < 2; ++i) {
            const float keep = (l & 8) ? acc[i + 2] : acc[i];
            const float send = (l & 8) ? acc[i] : acc[i + 2];
            acc[i] = keep + __shfl_xor(send, 8);
        }
        {
            const float keep = (l & 16) ? acc[1] : acc[0];
            const float send = (l & 16) ? acc[0] : acc[1];
            acc[0] = keep + __shfl_xor(send, 16);
        }
        const float tot = acc[0] + __shfl_xor(acc[0], 32);
        if (l < 32) {
            const int o = ((l & 1) << 4) | ((l & 2) << 2) | (l & 4)
                        | ((l & 8) >> 2) | ((l & 16) >> 4);   // bitrev5(l)
            rowLDS[o] = (tot + b2[o]) * 0.17677669529663687f; // /sqrt(32)
        }
    }
    __syncthreads();                           // row ready for all waves

    const float4 quad = ((const float4*)rowLDS)[t & 7];  // broadcast read

    // ---- stream the rectangle: thread t -> (line m = it*32 + t>>3, quad) --
    const int brmin = (dr > 0) ? dr : 0;
    const int irmin = (dc > 0) ? dc : 0;
    const int wc = 32 - ((dc < 0) ? -dc : dc);
    const int hb = 32 - ((dr < 0) ? -dr : dr);
    const int count = hb * wc;                 // 128-B lines for this pair
    const unsigned M = ((1u << 20) + (unsigned)wc - 1) / (unsigned)wc;
    const int mybase = t >> 3;                 // line slot within iteration
    const int o4 = t & 7;

    for (int m = mybase; m < count; m += 32) {
        const int q = (int)(((unsigned)m * M) >> 20);   // m / wc (exact)
        const int r = m - q * wc;                       // m % wc
        const int i = ((brmin + q) << 5) + (irmin + r);
        const int j = ((brmin + q - dr) << 5) + (irmin + r - dc);
        out[(((i << 10) + j) << 3) + o4] = quad;
    }
}

// ---------------------------------------------------------------------------
extern "C" void kernel_launch(void* const* d_in, const int* in_sizes, int n_in,
                              void* d_out, int out_size, void* d_ws, size_t ws_size,
                              hipStream_t stream) {
    // inputs: 0 seq_len 1 freqs(16) 2 W1(256*128) 3 b1(256) 4 W2(32*256)
    //         5 b2(32) 6 dr(S*S) 7 dc(S*S)
    const float* freqs = (const float*)d_in[1];
    const float* W1    = (const float*)d_in[2];
    const float* b1    = (const float*)d_in[3];
    const float* W2    = (const float*)d_in[4];
    const float* b2    = (const float*)d_in[5];
    float4* out = (float4*)d_out;

    float* P = (float*)d_ws;                   // 376*256*4 = 385 KB scratch

    gab_ptab_kernel   <<<PROWS, 256, 0, stream>>>(freqs, W1, P);
    gab_scatter_kernel<<<NPAIRS_TBL, 256, 0, stream>>>(P, b1, W2, b2, out);
}